// Round 7
// baseline (3467.501 us; speedup 1.0000x reference)
//
#include <hip/hip_runtime.h>
#include <hip/hip_bf16.h>
#include <stdint.h>

// Problem constants
#define BB 4
#define TT 2048
#define CC 2048
#define HH 16
#define DD 128
#define MM (BB*TT)   // 8192 rows

typedef __attribute__((ext_vector_type(8))) short bh8;   // 8 bf16 (4 VGPRs)
typedef __attribute__((ext_vector_type(4))) float fx4;   // MFMA 16x16 accumulator

__device__ inline ushort f2bf(float x) {
    union { float f; uint32_t u; } c; c.f = x;
    uint32_t lsb = (c.u >> 16) & 1u;
    return (ushort)((c.u + 0x7fffu + lsb) >> 16);
}

__device__ inline void async16(const void* g, void* l) {
    __builtin_amdgcn_global_load_lds(
        (const __attribute__((address_space(1))) uint32_t*)g,
        (__attribute__((address_space(3))) uint32_t*)l, 16, 0, 0);
}

// ---------------------------------------------------------------------------
// Fused fp32 -> bf16 convert for all 3 inputs (blockIdx.y selects tensor)
// ---------------------------------------------------------------------------
__global__ __launch_bounds__(256) void convert3_k(
    const float* __restrict__ i0, const float* __restrict__ i1,
    const float* __restrict__ i2,
    ushort* __restrict__ o0, ushort* __restrict__ o1, ushort* __restrict__ o2,
    int n)
{
    const float* in; ushort* out;
    switch (blockIdx.y) {
        case 0:  in = i0; out = o0; break;
        case 1:  in = i1; out = o1; break;
        default: in = i2; out = o2; break;
    }
    int i = (int)(blockIdx.x * 256 + threadIdx.x) * 4;
    if (i + 3 < n) {
        float4 v = *(const float4*)&in[i];
        ushort4 o;
        o.x = f2bf(v.x); o.y = f2bf(v.y); o.z = f2bf(v.z); o.w = f2bf(v.w);
        *(ushort4*)&out[i] = o;
    }
}

// ---------------------------------------------------------------------------
// Fused weight transpose+convert for all 4 weights (blockIdx.z selects).
// W[k][n] fp32 -> Wt[n][k] bf16 (CC x CC), ushort2 stores.
// ---------------------------------------------------------------------------
__global__ __launch_bounds__(256) void transpose4_w_k(
    const float* __restrict__ w0, const float* __restrict__ w1,
    const float* __restrict__ w2, const float* __restrict__ w3,
    ushort* __restrict__ t0, ushort* __restrict__ t1,
    ushort* __restrict__ t2, ushort* __restrict__ t3)
{
    const float* W; ushort* Wt;
    switch (blockIdx.z) {
        case 0:  W = w0; Wt = t0; break;
        case 1:  W = w1; Wt = t1; break;
        case 2:  W = w2; Wt = t2; break;
        default: W = w3; Wt = t3; break;
    }
    __shared__ __align__(16) ushort tile[32][33];
    const int n0 = blockIdx.x * 32, k0 = blockIdx.y * 32;
    const int tx = threadIdx.x, ty = threadIdx.y;   // (32, 8)
#pragma unroll
    for (int r = 0; r < 32; r += 8)
        tile[ty + r][tx] = f2bf(W[(size_t)(k0 + ty + r) * CC + n0 + tx]);  // [kl][nl]
    __syncthreads();
    const int tid = ty * 32 + tx;
    const int p = tid & 15;        // k-pair index
    const int row = tid >> 4;      // 0..15
#pragma unroll
    for (int rr = 0; rr < 2; ++rr) {
        const int n_row = row + rr * 16;
        ushort2 w2;
        w2.x = tile[2 * p][n_row];
        w2.y = tile[2 * p + 1][n_row];
        *(ushort2*)&Wt[(size_t)(n0 + n_row) * CC + k0 + 2 * p] = w2;
    }
}

// ---------------------------------------------------------------------------
// V transpose per head: V[b,t,h*D+d] bf16 -> Vt[((b*H+h)*D+d)*T + pnew(t)]
// pnew: within each 32-aligned t-block, with t = jj*16 + fg*4 + r:
//   p = fg*8 + jj*4 + r  (PV A-fragment k-slot order of swapped-QK^T softmax)
// ---------------------------------------------------------------------------
__global__ __launch_bounds__(256) void transpose_v_k(
    const ushort* __restrict__ V, ushort* __restrict__ Vt)
{
    __shared__ __align__(16) ushort tile[32][33];
    const int bh = blockIdx.z;
    const int b = bh >> 4, h = bh & 15;
    const int t0 = blockIdx.y * 32, d0 = blockIdx.x * 32;
    const int tx = threadIdx.x, ty = threadIdx.y;   // (32, 8)
    const ushort* Vp = V + (size_t)b * TT * CC + h * DD;
#pragma unroll
    for (int r = 0; r < 32; r += 8)
        tile[ty + r][tx] = Vp[(size_t)(t0 + ty + r) * CC + d0 + tx];  // [t][d]
    __syncthreads();
    ushort* Vtp = Vt + (size_t)bh * DD * TT;
    const int tt = t0 + tx;
    const int pnew = (tt & ~31) | (((tt >> 2) & 3) << 3) | (((tt >> 4) & 1) << 2) | (tt & 3);
#pragma unroll
    for (int r = 0; r < 32; r += 8)
        Vtp[(size_t)(d0 + ty + r) * TT + pnew] = tile[tx][ty + r];
}

// ---------------------------------------------------------------------------
// GEMM v12: occupancy-first geometry. BM=128, BN=256, BK=32, 8 waves (2Mx4N,
// 64x64 per wave), LDS 2 dbuf x 24KB (A 8KB | B 16KB) = 48KB -> 3 blocks/CU
// (24 waves/CU, 6/SIMD). Round-5/6 lesson: intra-block schedule edits inside
// the 1-block/CU lockstep paradigm gave +2% / -7%; the verified lever is
// cross-block TLP (m114: resident blocks at different loop phases overlap
// MFMA vs barrier/drain). Per K-tile: ONE barrier + precise vmcnt(0), then
// 8 ds_read_b128 + stage(t+1) (3 global_load_lds) + 16 MFMA; stage targets
// the other dbuf, stage(t+2) is issued only after barrier(t+1), and every
// wave's reads of buf cur are lgkm-complete before its MFMAs precede that
// barrier -> single barrier is race-free. Pair-XOR region format and
// staging lane map carried over (extent-halved; rp&7 invariant preserved).
// Grid: qkv (512,3) = 1536 blocks = exactly 2 rounds of 3/CU; o = 512.
// ---------------------------------------------------------------------------
template<int OUTF>
__device__ __forceinline__ void gemm_body(
    const ushort* A, const ushort* Bt, const float* bias, void* Cv, float osc)
{
    __shared__ __align__(16) char Gsm[2][24576];  // [dbuf][A 8KB | B 16KB]

    const int tid = (int)threadIdx.x;
    const int lane = tid & 63, wave = tid >> 6;
    const int fr = lane & 15, fg = lane >> 4;      // frag row / k-slot group
    const int wm = wave >> 2, wn = wave & 3;       // 2m x 4n wave grid

    // XCD-locality remap: xcd = bid%8 owns m_tiles [xcd*8, xcd*8+8) (4MB A
    // panel, L2-resident); its 64 blocks share B K-slices via L2.
    const int bid = (int)blockIdx.x;
    const int xcd = bid & 7, local = bid >> 3;     // local 0..63
    const int m_tile = xcd * 8 + (local >> 3);     // 64 m-tiles of 128 rows
    const int n_tile = local & 7;                  // 8 n-tiles of 256 cols
    const int m0 = m_tile * 128, n0 = n_tile * 256;

    const ushort* Ag = A  + (size_t)m0 * CC;
    const ushort* Bg = Bt + (size_t)n0 * CC;
    const int nt = CC / 32;                        // 64 K-tiles (BK=32)

    // stage tile t: A 8KB (1 load/thread) + B 16KB (2 loads/thread)
    auto STAGE = [&](int t) {
        if (t >= nt) return;
        char* base = Gsm[t & 1];
        const int kbase = t * 32;
        {
            const int u = tid;                     // A: u = rp*8 + s
            const int j = u >> 3, s = u & 7;
            const int ek = s ^ (j & 7);
            const int e = (ek >> 2) & 1, ks = ek & 3;
            async16(Ag + (size_t)(2 * j + e) * CC + kbase + ks * 8,
                    base + u * 16);
        }
#pragma unroll
        for (int l = 0; l < 2; ++l) {              // B: region base 8192
            const int u = l * 512 + tid;
            const int j = u >> 3, s = u & 7;
            const int ek = s ^ (j & 7);
            const int e = (ek >> 2) & 1, ks = ek & 3;
            async16(Bg + (size_t)(2 * j + e) * CC + kbase + ks * 8,
                    base + 8192 + u * 16);
        }
    };

    // fragment byte offsets (pair-XOR; +16 rows = +8 row-pairs = +1024B)
    const int slot = ((((fr & 1) << 2) | fg) ^ ((fr >> 1) & 7));
    const int offA = (wm * 32 + (fr >> 1)) * 128 + slot * 16;          // +mf*1024
    const int offB = 8192 + (wn * 32 + (fr >> 1)) * 128 + slot * 16;   // +nf*1024

    fx4 acc[4][4];
#pragma unroll
    for (int i = 0; i < 4; ++i)
#pragma unroll
        for (int j = 0; j < 4; ++j)
            acc[i][j] = (fx4){0.f, 0.f, 0.f, 0.f};

    STAGE(0);

#pragma unroll 1
    for (int t = 0; t < nt; ++t) {
        const char* kb = Gsm[t & 1];

        // tile boundary: own stage(t) loads done -> barrier -> all done
        asm volatile("s_waitcnt vmcnt(0)" ::: "memory");
        __builtin_amdgcn_sched_barrier(0);
        __builtin_amdgcn_s_barrier();
        __builtin_amdgcn_sched_barrier(0);

        bh8 a[4], b[4];
#pragma unroll
        for (int nf = 0; nf < 4; ++nf)
            b[nf] = *(const bh8*)(kb + offB + nf * 1024);
#pragma unroll
        for (int mf = 0; mf < 4; ++mf)
            a[mf] = *(const bh8*)(kb + offA + mf * 1024);

        STAGE(t + 1);   // other dbuf; issued before MFMA, lands during it

        __builtin_amdgcn_s_setprio(1);
#pragma unroll
        for (int mf = 0; mf < 4; ++mf)
#pragma unroll
            for (int nf = 0; nf < 4; ++nf)
                acc[mf][nf] = __builtin_amdgcn_mfma_f32_16x16x32_bf16(
                    a[mf], b[nf], acc[mf][nf], 0, 0, 0);
        __builtin_amdgcn_s_setprio(0);
    }

    // epilogue: C/D layout col=lane&15, row=(lane>>4)*4+reg
#pragma unroll
    for (int nf = 0; nf < 4; ++nf) {
        const int col = n0 + wn * 64 + nf * 16 + fr;
        const float bv = bias[col];
#pragma unroll
        for (int mf = 0; mf < 4; ++mf) {
            const int row = m0 + wm * 64 + mf * 16 + fg * 4;
#pragma unroll
            for (int r = 0; r < 4; ++r) {
                float v = (acc[mf][nf][r] + bv) * osc;
                if (OUTF)
                    ((float*)Cv)[(size_t)(row + r) * CC + col] = v;
                else
                    ((ushort*)Cv)[(size_t)(row + r) * CC + col] = f2bf(v);
            }
        }
    }
}

// Fused Q/K/V projection GEMM: grid (512, 3), blockIdx.y selects tensor.
__global__ __launch_bounds__(512, 6) void gemm_qkv_k(
    const ushort* __restrict__ Xq, const ushort* __restrict__ Xk,
    const ushort* __restrict__ Xv,
    const ushort* __restrict__ WqT, const ushort* __restrict__ WkT,
    const ushort* __restrict__ WvT,
    const float* __restrict__ bq, const float* __restrict__ bk,
    const float* __restrict__ bv,
    ushort* __restrict__ Qb, ushort* __restrict__ Kb, ushort* __restrict__ Vb)
{
    const ushort* A; const ushort* Bt; const float* bias; ushort* Cv; float osc;
    switch (blockIdx.y) {
        case 0:  A = Xq; Bt = WqT; bias = bq; Cv = Qb;
                 osc = 0.12751789836306614f; break;   // log2(e)/sqrt(128)
        case 1:  A = Xk; Bt = WkT; bias = bk; Cv = Kb; osc = 1.0f; break;
        default: A = Xv; Bt = WvT; bias = bv; Cv = Vb; osc = 1.0f; break;
    }
    gemm_body<0>(A, Bt, bias, Cv, osc);
}

// Output projection GEMM (fp32 out), grid (512)
__global__ __launch_bounds__(512, 6) void gemm_o_k(
    const ushort* __restrict__ A, const ushort* __restrict__ Bt,
    const float* __restrict__ bias, float* __restrict__ Cv)
{
    gemm_body<1>(A, Bt, bias, Cv, 1.0f);
}

// ---------------------------------------------------------------------------
// Flash attention v13 (round-4 verified, ~105us): one barrier per KV-tile,
// STAGE after the barrier, swapped-QK^T in-register softmax, ones-MFMA
// denominator, diagonal-tile skip, tile pairing, XCD swizzle. UNCHANGED.
// ---------------------------------------------------------------------------
__global__ __launch_bounds__(512, 4) void flash_attn_k(
    const ushort* __restrict__ Qm, const ushort* __restrict__ Km,
    const ushort* __restrict__ Vt, ushort* __restrict__ Om,
    const int* __restrict__ causal_p)
{
    __shared__ __align__(16) char Ksm[2][16384];   // [buf][kv=64][d=128] bf16
    __shared__ __align__(16) char Vsm[2][16384];   // [buf][d=128][pos=64] bf16

    const int tid = (int)threadIdx.x;
    const int lane = tid & 63, wave = tid >> 6;
    const int fr = lane & 15, fg = lane >> 4;
    const int causal = causal_p[0];

    const int d_raw = (int)blockIdx.x + 8 * ((int)blockIdx.y + 16 * (int)blockIdx.z);
    const int xcd = d_raw & 7, jj = d_raw >> 3;
    const int head_lin = xcd * 8 + (jj & 7);
    const int pi = jj >> 3;                   // 0..7 (pair index)
    const int h = head_lin & 15, b = head_lin >> 4;

    const ushort* Qp = Qm + (size_t)b * TT * CC + h * DD;
    const ushort* Kp = Km + (size_t)b * TT * CC + h * DD;
    const ushort* Vp = Vt + (size_t)(b * HH + h) * DD * TT;
    ushort* Op = Om + (size_t)b * TT * CC + h * DD;

    // all-ones bf16 B-fragment for the row-sum MFMA
    const bh8 onesf = {0x3F80, 0x3F80, 0x3F80, 0x3F80,
                       0x3F80, 0x3F80, 0x3F80, 0x3F80};

    auto STAGE = [&](int ti, int buf) {
        const int kv0 = ti * 64;
        {
            const int r0 = tid >> 4, s0 = tid & 15;
            async16(Kp + (size_t)(kv0 + r0) * CC + (s0 ^ (r0 & 15)) * 8,
                    Ksm[buf] + tid * 16);
            async16(Kp + (size_t)(kv0 + 32 + r0) * CC + (s0 ^ (r0 & 15)) * 8,
                    Ksm[buf] + 8192 + tid * 16);
        }
        {
            const int d0 = tid >> 3, s0 = tid & 7;
            async16(Vp + (size_t)d0 * TT + kv0 + (s0 ^ (d0 & 7)) * 8,
                    Vsm[buf] + tid * 16);
            async16(Vp + (size_t)(64 + d0) * TT + kv0 + (s0 ^ (d0 & 7)) * 8,
                    Vsm[buf] + 8192 + tid * 16);
        }
    };

#pragma unroll 1
    for (int pp = 0; pp < 2; ++pp) {
        const int tile = pp ? (15 - pi) : pi;
        const int q0 = tile * 128;
        const int qbase = q0 + wave * 16;
        const int q_idx = qbase + fr;         // this lane's q-row (swapped layout)

        bh8 qf[4];
#pragma unroll
        for (int s = 0; s < 4; ++s)
            qf[s] = *(const bh8*)&Qp[(size_t)(qbase + fr) * CC + s * 32 + fg * 8];

        fx4 o[8];
#pragma unroll
        for (int jn = 0; jn < 8; ++jn) o[jn] = (fx4){0.f, 0.f, 0.f, 0.f};
        fx4 o_l = (fx4){0.f, 0.f, 0.f, 0.f};

        const int nfull  = causal ? (q0 >> 6) : (TT / 64);
        const int ntiles = causal ? (nfull + 2) : (TT / 64);

        STAGE(0, 0);
#pragma unroll 1
        for (int t = 0; t < ntiles; ++t) {
            // top sync: own loads done -> barrier -> everyone's loads done
            asm volatile("s_waitcnt vmcnt(0)" ::: "memory");
            __builtin_amdgcn_sched_barrier(0);
            __builtin_amdgcn_s_barrier();
            __builtin_amdgcn_sched_barrier(0);
            if (t + 1 < ntiles) STAGE(t + 1, (t + 1) & 1);

            const int kv0 = t * 64;
            const char* kb = Ksm[t & 1];
            const char* vb = Vsm[t & 1];
            const bool domask = causal && (t >= nfull);
            const bool active = !domask || (kv0 <= qbase + 15);

            if (active) {
                // ---- QK^T, swapped: S^T layout; lane holds q=fr, kv=j*16+fg*4+r
                fx4 s4[4];
#pragma unroll
                for (int j = 0; j < 4; ++j) s4[j] = (fx4){0.f, 0.f, 0.f, 0.f};
                __builtin_amdgcn_s_setprio(1);
#pragma unroll
                for (int st = 0; st < 4; ++st) {
                    bh8 kf[4];
#pragma unroll
                    for (int j = 0; j < 4; ++j)
                        kf[j] = *(const bh8*)(kb + (j * 16 + fr) * 256 +
                                              ((st * 64 + fg * 16) ^ (fr << 4)));
#pragma unroll
                    for (int j = 0; j < 4; ++j)
                        s4[j] = __builtin_amdgcn_mfma_f32_16x16x32_bf16(
                            kf[j], qf[st], s4[j], 0, 0, 0);
                }
                __builtin_amdgcn_s_setprio(0);

                // ---- softmax + PV per 32-kv half; P never leaves registers
#pragma unroll
                for (int g = 0; g < 2; ++g) {
                    float pg[2][4];
#pragma unroll
                    for (int j2 = 0; j2 < 2; ++j2) {
                        const int jb = g * 2 + j2;
#pragma unroll
                        for (int r = 0; r < 4; ++r) {
                            float v = s4[jb][r];
                            if (domask && (kv0 + jb * 16 + fg * 4 + r > q_idx))
                                v = -1e30f;
                            pg[j2][r] = exp2f(v);
                        }
                    }
                    // pack to PV A-fragment: k-slot e = jj*4 + r
                    union { uint u[4]; bh8 h; } pk;
                    asm("v_cvt_pk_bf16_f32 %0, %1, %2"
                        : "=v"(pk.u[0]) : "v"(pg[0][0]), "v"(pg[0][1]));
                    asm("v_cvt_pk_bf16_f32 %0, %1, %2"
                        : "=v"(pk.u[1]) : "v"(pg[0][2]), "v"(pg[0][3]));
                    asm("v_cvt_pk_bf16_f32 %0, %1, %2"
                        : "=v"(pk.u[2]) : "v"(pg[1][0]), "v"(pg[1][1]));
                    asm("v_cvt_pk_bf16_f32 %0, %1, %2"
                        : "=v"(pk.u[3]) : "v"(pg[1][2]), "v"(pg[1][3]));
                    const bh8 pf = pk.h;

                    // denominator via matrix pipe: row-sum of this 32-kv half,
                    // D row = fg*4+r (matches epilogue rows), replicated on fr
                    o_l = __builtin_amdgcn_mfma_f32_16x16x32_bf16(
                        pf, onesf, o_l, 0, 0, 0);

                    __builtin_amdgcn_s_setprio(1);
#pragma unroll
                    for (int jn = 0; jn < 8; ++jn) {
                        bh8 vf = *(const bh8*)(vb + (jn * 16 + fr) * 128 +
                                               ((g * 64 + fg * 16) ^ ((fr & 7) << 4)));
                        o[jn] = __builtin_amdgcn_mfma_f32_16x16x32_bf16(
                            pf, vf, o[jn], 0, 0, 0);
                    }
                    __builtin_amdgcn_s_setprio(0);
                }
            }
        }

        // ---- epilogue: l already per-lane in D-layout (no shuffles)
#pragma unroll
        for (int r = 0; r < 4; ++r) {
            const float inv = 1.0f / o_l[r];
            const size_t rowoff = (size_t)(qbase + fg * 4 + r) * CC;
#pragma unroll
            for (int jn = 0; jn < 8; ++jn)
                Op[rowoff + jn * 16 + fr] = f2bf(o[jn][r] * inv);
        }
    }
}

// ---------------------------------------------------------------------------
extern "C" void kernel_launch(void* const* d_in, const int* in_sizes, int n_in,
                              void* d_out, int out_size, void* d_ws, size_t ws_size,
                              hipStream_t stream)
{
    (void)in_sizes; (void)n_in; (void)out_size;
    const float* querys = (const float*)d_in[0];
    const float* keys   = (const float*)d_in[1];
    const float* values = (const float*)d_in[2];
    const float* Wq = (const float*)d_in[3];
    const float* bq = (const float*)d_in[4];
    const float* Wk = (const float*)d_in[5];
    const float* bk = (const float*)d_in[6];
    const float* Wv = (const float*)d_in[7];
    const float* bv = (const float*)d_in[8];
    const float* Wo = (const float*)d_in[9];
    const float* bo = (const float*)d_in[10];
    const int* is_causal = (const int*)d_in[11];

    const size_t WBYTES = (size_t)CC * CC * 2;   // 8 MiB per weight
    const size_t XBYTES = (size_t)MM * CC * 2;   // 32 MiB per activation
    if (ws_size < 4 * WBYTES + 4 * XBYTES) return;  // need 160 MiB

    uint8_t* ws = (uint8_t*)d_ws;
    ushort* WqT = (ushort*)(ws);
    ushort* WkT = (ushort*)(ws + WBYTES);
    ushort* WvT = (ushort*)(ws + 2 * WBYTES);
    ushort* WoT = (ushort*)(ws + 3 * WBYTES);
    uint8_t* act = ws + 4 * WBYTES;
    ushort* Xq = (ushort*)(act);                 // later: Kb
    ushort* Xk = (ushort*)(act + XBYTES);        // later: Vb, then attn-out
    ushort* Xv = (ushort*)(act + 2 * XBYTES);    // later: Vt
    ushort* Qb = (ushort*)(act + 3 * XBYTES);
    ushort* Kb = Xq;
    ushort* Vb = Xk;
    ushort* Vt = Xv;
    ushort* Ob = Xk;   // attn output overwrites Vb (dead after transpose_v)

    dim3 tb(32, 8);
    transpose4_w_k<<<dim3(CC / 32, CC / 32, 4), tb, 0, stream>>>(
        Wq, Wk, Wv, Wo, WqT, WkT, WvT, WoT);

    const int nX = MM * CC;
    convert3_k<<<dim3(nX / 4 / 256, 3), 256, 0, stream>>>(
        querys, keys, values, Xq, Xk, Xv, nX);

    // fused Q/K/V projections: 1536 blocks, 3/CU resident, 2 full rounds
    gemm_qkv_k<<<dim3((MM / 128) * (CC / 256), 3), 512, 0, stream>>>(
        Xq, Xk, Xv, WqT, WkT, WvT, bq, bk, bv, Qb, Kb, Vb);

    dim3 gvt(DD / 32, TT / 32, BB * HH);
    transpose_v_k<<<gvt, tb, 0, stream>>>(Vb, Vt);

    dim3 ga(8, HH, BB);   // pair index x head x batch, 512 threads
    flash_attn_k<<<ga, 512, 0, stream>>>(Qb, Kb, Vt, Ob, is_causal);

    gemm_o_k<<<dim3((MM / 128) * (CC / 256)), 512, 0, stream>>>(
        Ob, WoT, bo, (float*)d_out);
}

// Round 8
// 460.607 us; speedup vs baseline: 7.5281x; 7.5281x over previous
//
#include <hip/hip_runtime.h>
#include <hip/hip_bf16.h>
#include <stdint.h>

// Problem constants
#define BB 4
#define TT 2048
#define CC 2048
#define HH 16
#define DD 128
#define MM (BB*TT)   // 8192 rows

typedef __attribute__((ext_vector_type(8))) short bh8;   // 8 bf16 (4 VGPRs)
typedef __attribute__((ext_vector_type(4))) float fx4;   // MFMA 16x16 accumulator

__device__ inline ushort f2bf(float x) {
    union { float f; uint32_t u; } c; c.f = x;
    uint32_t lsb = (c.u >> 16) & 1u;
    return (ushort)((c.u + 0x7fffu + lsb) >> 16);
}

__device__ inline void async16(const void* g, void* l) {
    __builtin_amdgcn_global_load_lds(
        (const __attribute__((address_space(1))) uint32_t*)g,
        (__attribute__((address_space(3))) uint32_t*)l, 16, 0, 0);
}

// ---------------------------------------------------------------------------
// Fused fp32 -> bf16 convert for all 3 inputs (blockIdx.y selects tensor)
// ---------------------------------------------------------------------------
__global__ __launch_bounds__(256) void convert3_k(
    const float* __restrict__ i0, const float* __restrict__ i1,
    const float* __restrict__ i2,
    ushort* __restrict__ o0, ushort* __restrict__ o1, ushort* __restrict__ o2,
    int n)
{
    const float* in; ushort* out;
    switch (blockIdx.y) {
        case 0:  in = i0; out = o0; break;
        case 1:  in = i1; out = o1; break;
        default: in = i2; out = o2; break;
    }
    int i = (int)(blockIdx.x * 256 + threadIdx.x) * 4;
    if (i + 3 < n) {
        float4 v = *(const float4*)&in[i];
        ushort4 o;
        o.x = f2bf(v.x); o.y = f2bf(v.y); o.z = f2bf(v.z); o.w = f2bf(v.w);
        *(ushort4*)&out[i] = o;
    }
}

// ---------------------------------------------------------------------------
// Fused weight transpose+convert for all 4 weights (blockIdx.z selects).
// W[k][n] fp32 -> Wt[n][k] bf16 (CC x CC), ushort2 stores.
// ---------------------------------------------------------------------------
__global__ __launch_bounds__(256) void transpose4_w_k(
    const float* __restrict__ w0, const float* __restrict__ w1,
    const float* __restrict__ w2, const float* __restrict__ w3,
    ushort* __restrict__ t0, ushort* __restrict__ t1,
    ushort* __restrict__ t2, ushort* __restrict__ t3)
{
    const float* W; ushort* Wt;
    switch (blockIdx.z) {
        case 0:  W = w0; Wt = t0; break;
        case 1:  W = w1; Wt = t1; break;
        case 2:  W = w2; Wt = t2; break;
        default: W = w3; Wt = t3; break;
    }
    __shared__ __align__(16) ushort tile[32][33];
    const int n0 = blockIdx.x * 32, k0 = blockIdx.y * 32;
    const int tx = threadIdx.x, ty = threadIdx.y;   // (32, 8)
#pragma unroll
    for (int r = 0; r < 32; r += 8)
        tile[ty + r][tx] = f2bf(W[(size_t)(k0 + ty + r) * CC + n0 + tx]);  // [kl][nl]
    __syncthreads();
    const int tid = ty * 32 + tx;
    const int p = tid & 15;        // k-pair index
    const int row = tid >> 4;      // 0..15
#pragma unroll
    for (int rr = 0; rr < 2; ++rr) {
        const int n_row = row + rr * 16;
        ushort2 w2;
        w2.x = tile[2 * p][n_row];
        w2.y = tile[2 * p + 1][n_row];
        *(ushort2*)&Wt[(size_t)(n0 + n_row) * CC + k0 + 2 * p] = w2;
    }
}

// ---------------------------------------------------------------------------
// V transpose per head: V[b,t,h*D+d] bf16 -> Vt[((b*H+h)*D+d)*T + pnew(t)]
// pnew: within each 32-aligned t-block, with t = jj*16 + fg*4 + r:
//   p = fg*8 + jj*4 + r  (PV A-fragment k-slot order of swapped-QK^T softmax)
// ---------------------------------------------------------------------------
__global__ __launch_bounds__(256) void transpose_v_k(
    const ushort* __restrict__ V, ushort* __restrict__ Vt)
{
    __shared__ __align__(16) ushort tile[32][33];
    const int bh = blockIdx.z;
    const int b = bh >> 4, h = bh & 15;
    const int t0 = blockIdx.y * 32, d0 = blockIdx.x * 32;
    const int tx = threadIdx.x, ty = threadIdx.y;   // (32, 8)
    const ushort* Vp = V + (size_t)b * TT * CC + h * DD;
#pragma unroll
    for (int r = 0; r < 32; r += 8)
        tile[ty + r][tx] = Vp[(size_t)(t0 + ty + r) * CC + d0 + tx];  // [t][d]
    __syncthreads();
    ushort* Vtp = Vt + (size_t)bh * DD * TT;
    const int tt = t0 + tx;
    const int pnew = (tt & ~31) | (((tt >> 2) & 3) << 3) | (((tt >> 4) & 1) << 2) | (tt & 3);
#pragma unroll
    for (int r = 0; r < 32; r += 8)
        Vtp[(size_t)(d0 + ty + r) * TT + pnew] = tile[tx][ty + r];
}

// ---------------------------------------------------------------------------
// GEMM v12b: round-7 geometry (BM=128, BN=256, BK=32, 8 waves 2Mx4N 64x64,
// LDS 48KB, one barrier + vmcnt(0) per K-tile, stage-after-barrier) with the
// REGISTER BUDGET FIXED. Round-7 failure was NOT the schedule: __launch_
// bounds__(512,6) capped VGPR at ~85, the ~120-reg working set (acc 64 +
// frags 32 + addr) spilled to scratch -> 12GB scratch traffic, VGPR_Count
// 40, MfmaUtil 3.4. Geometry/swizzle/lane-map were harness-verified correct.
// Fix: __launch_bounds__(512, 4) -> VGPR cap 128 (fits ~120, no spill),
// guaranteed 16 waves/CU = 2 blocks/CU; LDS 48KB also allows 2. Two
// resident blocks at independent loop phases cover each other's
// vmcnt(0)+barrier drains (m114 TLP mechanism) -- untestable at the 256^2
// tile's 128KB LDS (1 block/CU). Revert baseline: v10 at 212us.
// ---------------------------------------------------------------------------
template<int OUTF>
__device__ __forceinline__ void gemm_body(
    const ushort* A, const ushort* Bt, const float* bias, void* Cv, float osc)
{
    __shared__ __align__(16) char Gsm[2][24576];  // [dbuf][A 8KB | B 16KB]

    const int tid = (int)threadIdx.x;
    const int lane = tid & 63, wave = tid >> 6;
    const int fr = lane & 15, fg = lane >> 4;      // frag row / k-slot group
    const int wm = wave >> 2, wn = wave & 3;       // 2m x 4n wave grid

    // XCD-locality remap: xcd = bid%8 owns m_tiles [xcd*8, xcd*8+8) (4MB A
    // panel, L2-resident); its 64 blocks share B K-slices via L2.
    const int bid = (int)blockIdx.x;
    const int xcd = bid & 7, local = bid >> 3;     // local 0..63
    const int m_tile = xcd * 8 + (local >> 3);     // 64 m-tiles of 128 rows
    const int n_tile = local & 7;                  // 8 n-tiles of 256 cols
    const int m0 = m_tile * 128, n0 = n_tile * 256;

    const ushort* Ag = A  + (size_t)m0 * CC;
    const ushort* Bg = Bt + (size_t)n0 * CC;
    const int nt = CC / 32;                        // 64 K-tiles (BK=32)

    // stage tile t: A 8KB (1 load/thread) + B 16KB (2 loads/thread)
    auto STAGE = [&](int t) {
        if (t >= nt) return;
        char* base = Gsm[t & 1];
        const int kbase = t * 32;
        {
            const int u = tid;                     // A: u = rp*8 + s
            const int j = u >> 3, s = u & 7;
            const int ek = s ^ (j & 7);
            const int e = (ek >> 2) & 1, ks = ek & 3;
            async16(Ag + (size_t)(2 * j + e) * CC + kbase + ks * 8,
                    base + u * 16);
        }
#pragma unroll
        for (int l = 0; l < 2; ++l) {              // B: region base 8192
            const int u = l * 512 + tid;
            const int j = u >> 3, s = u & 7;
            const int ek = s ^ (j & 7);
            const int e = (ek >> 2) & 1, ks = ek & 3;
            async16(Bg + (size_t)(2 * j + e) * CC + kbase + ks * 8,
                    base + 8192 + u * 16);
        }
    };

    // fragment byte offsets (pair-XOR; +16 rows = +8 row-pairs = +1024B)
    const int slot = ((((fr & 1) << 2) | fg) ^ ((fr >> 1) & 7));
    const int offA = (wm * 32 + (fr >> 1)) * 128 + slot * 16;          // +mf*1024
    const int offB = 8192 + (wn * 32 + (fr >> 1)) * 128 + slot * 16;   // +nf*1024

    fx4 acc[4][4];
#pragma unroll
    for (int i = 0; i < 4; ++i)
#pragma unroll
        for (int j = 0; j < 4; ++j)
            acc[i][j] = (fx4){0.f, 0.f, 0.f, 0.f};

    STAGE(0);

#pragma unroll 1
    for (int t = 0; t < nt; ++t) {
        const char* kb = Gsm[t & 1];

        // tile boundary: own stage(t) loads done -> barrier -> all done
        asm volatile("s_waitcnt vmcnt(0)" ::: "memory");
        __builtin_amdgcn_sched_barrier(0);
        __builtin_amdgcn_s_barrier();
        __builtin_amdgcn_sched_barrier(0);

        bh8 a[4], b[4];
#pragma unroll
        for (int nf = 0; nf < 4; ++nf)
            b[nf] = *(const bh8*)(kb + offB + nf * 1024);
#pragma unroll
        for (int mf = 0; mf < 4; ++mf)
            a[mf] = *(const bh8*)(kb + offA + mf * 1024);

        STAGE(t + 1);   // other dbuf; issued before MFMA, lands during it

        __builtin_amdgcn_s_setprio(1);
#pragma unroll
        for (int mf = 0; mf < 4; ++mf)
#pragma unroll
            for (int nf = 0; nf < 4; ++nf)
                acc[mf][nf] = __builtin_amdgcn_mfma_f32_16x16x32_bf16(
                    a[mf], b[nf], acc[mf][nf], 0, 0, 0);
        __builtin_amdgcn_s_setprio(0);
    }

    // epilogue: C/D layout col=lane&15, row=(lane>>4)*4+reg
#pragma unroll
    for (int nf = 0; nf < 4; ++nf) {
        const int col = n0 + wn * 64 + nf * 16 + fr;
        const float bv = bias[col];
#pragma unroll
        for (int mf = 0; mf < 4; ++mf) {
            const int row = m0 + wm * 64 + mf * 16 + fg * 4;
#pragma unroll
            for (int r = 0; r < 4; ++r) {
                float v = (acc[mf][nf][r] + bv) * osc;
                if (OUTF)
                    ((float*)Cv)[(size_t)(row + r) * CC + col] = v;
                else
                    ((ushort*)Cv)[(size_t)(row + r) * CC + col] = f2bf(v);
            }
        }
    }
}

// Fused Q/K/V projection GEMM: grid (512, 3), blockIdx.y selects tensor.
// launch_bounds (512, 4): VGPR cap 128 -> no spill, 2 blocks/CU.
__global__ __launch_bounds__(512, 4) void gemm_qkv_k(
    const ushort* __restrict__ Xq, const ushort* __restrict__ Xk,
    const ushort* __restrict__ Xv,
    const ushort* __restrict__ WqT, const ushort* __restrict__ WkT,
    const ushort* __restrict__ WvT,
    const float* __restrict__ bq, const float* __restrict__ bk,
    const float* __restrict__ bv,
    ushort* __restrict__ Qb, ushort* __restrict__ Kb, ushort* __restrict__ Vb)
{
    const ushort* A; const ushort* Bt; const float* bias; ushort* Cv; float osc;
    switch (blockIdx.y) {
        case 0:  A = Xq; Bt = WqT; bias = bq; Cv = Qb;
                 osc = 0.12751789836306614f; break;   // log2(e)/sqrt(128)
        case 1:  A = Xk; Bt = WkT; bias = bk; Cv = Kb; osc = 1.0f; break;
        default: A = Xv; Bt = WvT; bias = bv; Cv = Vb; osc = 1.0f; break;
    }
    gemm_body<0>(A, Bt, bias, Cv, osc);
}

// Output projection GEMM (fp32 out), grid (512)
__global__ __launch_bounds__(512, 4) void gemm_o_k(
    const ushort* __restrict__ A, const ushort* __restrict__ Bt,
    const float* __restrict__ bias, float* __restrict__ Cv)
{
    gemm_body<1>(A, Bt, bias, Cv, 1.0f);
}

// ---------------------------------------------------------------------------
// Flash attention v13 (round-4 verified, ~105us): one barrier per KV-tile,
// STAGE after the barrier, swapped-QK^T in-register softmax, ones-MFMA
// denominator, diagonal-tile skip, tile pairing, XCD swizzle. UNCHANGED.
// ---------------------------------------------------------------------------
__global__ __launch_bounds__(512, 4) void flash_attn_k(
    const ushort* __restrict__ Qm, const ushort* __restrict__ Km,
    const ushort* __restrict__ Vt, ushort* __restrict__ Om,
    const int* __restrict__ causal_p)
{
    __shared__ __align__(16) char Ksm[2][16384];   // [buf][kv=64][d=128] bf16
    __shared__ __align__(16) char Vsm[2][16384];   // [buf][d=128][pos=64] bf16

    const int tid = (int)threadIdx.x;
    const int lane = tid & 63, wave = tid >> 6;
    const int fr = lane & 15, fg = lane >> 4;
    const int causal = causal_p[0];

    const int d_raw = (int)blockIdx.x + 8 * ((int)blockIdx.y + 16 * (int)blockIdx.z);
    const int xcd = d_raw & 7, jj = d_raw >> 3;
    const int head_lin = xcd * 8 + (jj & 7);
    const int pi = jj >> 3;                   // 0..7 (pair index)
    const int h = head_lin & 15, b = head_lin >> 4;

    const ushort* Qp = Qm + (size_t)b * TT * CC + h * DD;
    const ushort* Kp = Km + (size_t)b * TT * CC + h * DD;
    const ushort* Vp = Vt + (size_t)(b * HH + h) * DD * TT;
    ushort* Op = Om + (size_t)b * TT * CC + h * DD;

    // all-ones bf16 B-fragment for the row-sum MFMA
    const bh8 onesf = {0x3F80, 0x3F80, 0x3F80, 0x3F80,
                       0x3F80, 0x3F80, 0x3F80, 0x3F80};

    auto STAGE = [&](int ti, int buf) {
        const int kv0 = ti * 64;
        {
            const int r0 = tid >> 4, s0 = tid & 15;
            async16(Kp + (size_t)(kv0 + r0) * CC + (s0 ^ (r0 & 15)) * 8,
                    Ksm[buf] + tid * 16);
            async16(Kp + (size_t)(kv0 + 32 + r0) * CC + (s0 ^ (r0 & 15)) * 8,
                    Ksm[buf] + 8192 + tid * 16);
        }
        {
            const int d0 = tid >> 3, s0 = tid & 7;
            async16(Vp + (size_t)d0 * TT + kv0 + (s0 ^ (d0 & 7)) * 8,
                    Vsm[buf] + tid * 16);
            async16(Vp + (size_t)(64 + d0) * TT + kv0 + (s0 ^ (d0 & 7)) * 8,
                    Vsm[buf] + 8192 + tid * 16);
        }
    };

#pragma unroll 1
    for (int pp = 0; pp < 2; ++pp) {
        const int tile = pp ? (15 - pi) : pi;
        const int q0 = tile * 128;
        const int qbase = q0 + wave * 16;
        const int q_idx = qbase + fr;         // this lane's q-row (swapped layout)

        bh8 qf[4];
#pragma unroll
        for (int s = 0; s < 4; ++s)
            qf[s] = *(const bh8*)&Qp[(size_t)(qbase + fr) * CC + s * 32 + fg * 8];

        fx4 o[8];
#pragma unroll
        for (int jn = 0; jn < 8; ++jn) o[jn] = (fx4){0.f, 0.f, 0.f, 0.f};
        fx4 o_l = (fx4){0.f, 0.f, 0.f, 0.f};

        const int nfull  = causal ? (q0 >> 6) : (TT / 64);
        const int ntiles = causal ? (nfull + 2) : (TT / 64);

        STAGE(0, 0);
#pragma unroll 1
        for (int t = 0; t < ntiles; ++t) {
            // top sync: own loads done -> barrier -> everyone's loads done
            asm volatile("s_waitcnt vmcnt(0)" ::: "memory");
            __builtin_amdgcn_sched_barrier(0);
            __builtin_amdgcn_s_barrier();
            __builtin_amdgcn_sched_barrier(0);
            if (t + 1 < ntiles) STAGE(t + 1, (t + 1) & 1);

            const int kv0 = t * 64;
            const char* kb = Ksm[t & 1];
            const char* vb = Vsm[t & 1];
            const bool domask = causal && (t >= nfull);
            const bool active = !domask || (kv0 <= qbase + 15);

            if (active) {
                // ---- QK^T, swapped: S^T layout; lane holds q=fr, kv=j*16+fg*4+r
                fx4 s4[4];
#pragma unroll
                for (int j = 0; j < 4; ++j) s4[j] = (fx4){0.f, 0.f, 0.f, 0.f};
                __builtin_amdgcn_s_setprio(1);
#pragma unroll
                for (int st = 0; st < 4; ++st) {
                    bh8 kf[4];
#pragma unroll
                    for (int j = 0; j < 4; ++j)
                        kf[j] = *(const bh8*)(kb + (j * 16 + fr) * 256 +
                                              ((st * 64 + fg * 16) ^ (fr << 4)));
#pragma unroll
                    for (int j = 0; j < 4; ++j)
                        s4[j] = __builtin_amdgcn_mfma_f32_16x16x32_bf16(
                            kf[j], qf[st], s4[j], 0, 0, 0);
                }
                __builtin_amdgcn_s_setprio(0);

                // ---- softmax + PV per 32-kv half; P never leaves registers
#pragma unroll
                for (int g = 0; g < 2; ++g) {
                    float pg[2][4];
#pragma unroll
                    for (int j2 = 0; j2 < 2; ++j2) {
                        const int jb = g * 2 + j2;
#pragma unroll
                        for (int r = 0; r < 4; ++r) {
                            float v = s4[jb][r];
                            if (domask && (kv0 + jb * 16 + fg * 4 + r > q_idx))
                                v = -1e30f;
                            pg[j2][r] = exp2f(v);
                        }
                    }
                    // pack to PV A-fragment: k-slot e = jj*4 + r
                    union { uint u[4]; bh8 h; } pk;
                    asm("v_cvt_pk_bf16_f32 %0, %1, %2"
                        : "=v"(pk.u[0]) : "v"(pg[0][0]), "v"(pg[0][1]));
                    asm("v_cvt_pk_bf16_f32 %0, %1, %2"
                        : "=v"(pk.u[1]) : "v"(pg[0][2]), "v"(pg[0][3]));
                    asm("v_cvt_pk_bf16_f32 %0, %1, %2"
                        : "=v"(pk.u[2]) : "v"(pg[1][0]), "v"(pg[1][1]));
                    asm("v_cvt_pk_bf16_f32 %0, %1, %2"
                        : "=v"(pk.u[3]) : "v"(pg[1][2]), "v"(pg[1][3]));
                    const bh8 pf = pk.h;

                    // denominator via matrix pipe: row-sum of this 32-kv half,
                    // D row = fg*4+r (matches epilogue rows), replicated on fr
                    o_l = __builtin_amdgcn_mfma_f32_16x16x32_bf16(
                        pf, onesf, o_l, 0, 0, 0);

                    __builtin_amdgcn_s_setprio(1);
#pragma unroll
                    for (int jn = 0; jn < 8; ++jn) {
                        bh8 vf = *(const bh8*)(vb + (jn * 16 + fr) * 128 +
                                               ((g * 64 + fg * 16) ^ ((fr & 7) << 4)));
                        o[jn] = __builtin_amdgcn_mfma_f32_16x16x32_bf16(
                            pf, vf, o[jn], 0, 0, 0);
                    }
                    __builtin_amdgcn_s_setprio(0);
                }
            }
        }

        // ---- epilogue: l already per-lane in D-layout (no shuffles)
#pragma unroll
        for (int r = 0; r < 4; ++r) {
            const float inv = 1.0f / o_l[r];
            const size_t rowoff = (size_t)(qbase + fg * 4 + r) * CC;
#pragma unroll
            for (int jn = 0; jn < 8; ++jn)
                Op[rowoff + jn * 16 + fr] = f2bf(o[jn][r] * inv);
        }
    }
}

// ---------------------------------------------------------------------------
extern "C" void kernel_launch(void* const* d_in, const int* in_sizes, int n_in,
                              void* d_out, int out_size, void* d_ws, size_t ws_size,
                              hipStream_t stream)
{
    (void)in_sizes; (void)n_in; (void)out_size;
    const float* querys = (const float*)d_in[0];
    const float* keys   = (const float*)d_in[1];
    const float* values = (const float*)d_in[2];
    const float* Wq = (const float*)d_in[3];
    const float* bq = (const float*)d_in[4];
    const float* Wk = (const float*)d_in[5];
    const float* bk = (const float*)d_in[6];
    const float* Wv = (const float*)d_in[7];
    const float* bv = (const float*)d_in[8];
    const float* Wo = (const float*)d_in[9];
    const float* bo = (const float*)d_in[10];
    const int* is_causal = (const int*)d_in[11];

    const size_t WBYTES = (size_t)CC * CC * 2;   // 8 MiB per weight
    const size_t XBYTES = (size_t)MM * CC * 2;   // 32 MiB per activation
    if (ws_size < 4 * WBYTES + 4 * XBYTES) return;  // need 160 MiB

    uint8_t* ws = (uint8_t*)d_ws;
    ushort* WqT = (ushort*)(ws);
    ushort* WkT = (ushort*)(ws + WBYTES);
    ushort* WvT = (ushort*)(ws + 2 * WBYTES);
    ushort* WoT = (ushort*)(ws + 3 * WBYTES);
    uint8_t* act = ws + 4 * WBYTES;
    ushort* Xq = (ushort*)(act);                 // later: Kb
    ushort* Xk = (ushort*)(act + XBYTES);        // later: Vb, then attn-out
    ushort* Xv = (ushort*)(act + 2 * XBYTES);    // later: Vt
    ushort* Qb = (ushort*)(act + 3 * XBYTES);
    ushort* Kb = Xq;
    ushort* Vb = Xk;
    ushort* Vt = Xv;
    ushort* Ob = Xk;   // attn output overwrites Vb (dead after transpose_v)

    dim3 tb(32, 8);
    transpose4_w_k<<<dim3(CC / 32, CC / 32, 4), tb, 0, stream>>>(
        Wq, Wk, Wv, Wo, WqT, WkT, WvT, WoT);

    const int nX = MM * CC;
    convert3_k<<<dim3(nX / 4 / 256, 3), 256, 0, stream>>>(
        querys, keys, values, Xq, Xk, Xv, nX);

    // fused Q/K/V projections: 1536 blocks, 2 blocks/CU resident
    gemm_qkv_k<<<dim3((MM / 128) * (CC / 256), 3), 512, 0, stream>>>(
        Xq, Xk, Xv, WqT, WkT, WvT, bq, bk, bv, Qb, Kb, Vb);

    dim3 gvt(DD / 32, TT / 32, BB * HH);
    transpose_v_k<<<gvt, tb, 0, stream>>>(Vb, Vt);

    dim3 ga(8, HH, BB);   // pair index x head x batch, 512 threads
    flash_attn_k<<<ga, 512, 0, stream>>>(Qb, Kb, Vt, Ob, is_causal);

    gemm_o_k<<<dim3((MM / 128) * (CC / 256)), 512, 0, stream>>>(
        Ob, WoT, bo, (float*)d_out);
}

// Round 10
// 425.211 us; speedup vs baseline: 8.1548x; 1.0832x over previous
//
#include <hip/hip_runtime.h>
#include <hip/hip_bf16.h>
#include <stdint.h>

// Problem constants
#define BB 4
#define TT 2048
#define CC 2048
#define HH 16
#define DD 128
#define MM (BB*TT)   // 8192 rows

typedef __attribute__((ext_vector_type(8))) short bh8;   // 8 bf16 (4 VGPRs)
typedef __attribute__((ext_vector_type(4))) float fx4;   // MFMA 16x16 accumulator

__device__ inline ushort f2bf(float x) {
    union { float f; uint32_t u; } c; c.f = x;
    uint32_t lsb = (c.u >> 16) & 1u;
    return (ushort)((c.u + 0x7fffu + lsb) >> 16);
}

__device__ inline void async16(const void* g, void* l) {
    __builtin_amdgcn_global_load_lds(
        (const __attribute__((address_space(1))) uint32_t*)g,
        (__attribute__((address_space(3))) uint32_t*)l, 16, 0, 0);
}

// ---------------------------------------------------------------------------
// Fused fp32 -> bf16 convert for all 3 inputs (blockIdx.y selects tensor)
// ---------------------------------------------------------------------------
__global__ __launch_bounds__(256) void convert3_k(
    const float* __restrict__ i0, const float* __restrict__ i1,
    const float* __restrict__ i2,
    ushort* __restrict__ o0, ushort* __restrict__ o1, ushort* __restrict__ o2,
    int n)
{
    const float* in; ushort* out;
    switch (blockIdx.y) {
        case 0:  in = i0; out = o0; break;
        case 1:  in = i1; out = o1; break;
        default: in = i2; out = o2; break;
    }
    int i = (int)(blockIdx.x * 256 + threadIdx.x) * 4;
    if (i + 3 < n) {
        float4 v = *(const float4*)&in[i];
        ushort4 o;
        o.x = f2bf(v.x); o.y = f2bf(v.y); o.z = f2bf(v.z); o.w = f2bf(v.w);
        *(ushort4*)&out[i] = o;
    }
}

// ---------------------------------------------------------------------------
// Fused weight transpose+convert for all 4 weights (blockIdx.z selects).
// W[k][n] fp32 -> Wt[n][k] bf16 (CC x CC), ushort2 stores.
// ---------------------------------------------------------------------------
__global__ __launch_bounds__(256) void transpose4_w_k(
    const float* __restrict__ w0, const float* __restrict__ w1,
    const float* __restrict__ w2, const float* __restrict__ w3,
    ushort* __restrict__ t0, ushort* __restrict__ t1,
    ushort* __restrict__ t2, ushort* __restrict__ t3)
{
    const float* W; ushort* Wt;
    switch (blockIdx.z) {
        case 0:  W = w0; Wt = t0; break;
        case 1:  W = w1; Wt = t1; break;
        case 2:  W = w2; Wt = t2; break;
        default: W = w3; Wt = t3; break;
    }
    __shared__ __align__(16) ushort tile[32][33];
    const int n0 = blockIdx.x * 32, k0 = blockIdx.y * 32;
    const int tx = threadIdx.x, ty = threadIdx.y;   // (32, 8)
#pragma unroll
    for (int r = 0; r < 32; r += 8)
        tile[ty + r][tx] = f2bf(W[(size_t)(k0 + ty + r) * CC + n0 + tx]);  // [kl][nl]
    __syncthreads();
    const int tid = ty * 32 + tx;
    const int p = tid & 15;        // k-pair index
    const int row = tid >> 4;      // 0..15
#pragma unroll
    for (int rr = 0; rr < 2; ++rr) {
        const int n_row = row + rr * 16;
        ushort2 w2;
        w2.x = tile[2 * p][n_row];
        w2.y = tile[2 * p + 1][n_row];
        *(ushort2*)&Wt[(size_t)(n0 + n_row) * CC + k0 + 2 * p] = w2;
    }
}

// ---------------------------------------------------------------------------
// GEMM v10' (round-5 verified, 212us): m201-template port, K-HALF
// granularity, 256x256 tile, BK=64, 8 waves (2Mx4N), XCD-locality remap,
// single counted vmcnt per K-tile, staging one phase early.
// Rounds 6-8: three restructures all regressed vs this schedule -> locked.
// OUTF==2 epilogue writes V-projection output DIRECTLY in the flash Vt
// layout [bh][d][pnew(t)], eliminating transpose_v_k.
// NOTE (round-9 compile failure): Gsm is declared in the CALLING __global__
// kernel and passed in -- inlining two gemm_body<OUTF> instantiations each
// with their own static __shared__ array doubled LDS to 256KB > 160KB.
// ---------------------------------------------------------------------------
template<int OUTF>
__device__ __forceinline__ void gemm_body(
    char (*Gsm)[65536],                           // [2][65536] shared, caller-owned
    const ushort* A, const ushort* Bt, const float* bias, void* Cv, float osc)
{
    const int tid = (int)threadIdx.x;
    const int lane = tid & 63, wave = tid >> 6;
    const int fr = lane & 15, fg = lane >> 4;      // frag row / k-slot group
    const int wm = wave >> 2, wn = wave & 3;       // 2m x 4n wave grid

    // XCD-locality remap: xcd = bid%8 owns m_tiles [xcd*4, xcd*4+4).
    const int bid = (int)blockIdx.x;
    const int xcd = bid & 7, local = bid >> 3;
    const int m_tile = xcd * 4 + (local >> 3);
    const int n_tile = local & 7;
    const int m0 = m_tile * 256, n0 = n_tile * 256;

    const ushort* Ag = A  + (size_t)m0 * CC;
    const ushort* Bg = Bt + (size_t)n0 * CC;
    const int nt = CC / 64;                        // 32 K-tiles (BK=64)

    // stage group g of tile t: g0=A.k0 g1=B.k0 g2=A.k1 g3=B.k1 (2 loads)
    auto STAGE_G = [&](int t, int g) {
        if (t >= nt) return;
        const int khalf = g >> 1, isB = g & 1;
        char* base = Gsm[t & 1] + isB * 32768 + khalf * 16384;
        const ushort* src = isB ? Bg : Ag;
        const int kbase = t * 64 + khalf * 32;
#pragma unroll
        for (int l = 0; l < 2; ++l) {
            const int u = l * 512 + tid;
            const int j = u >> 3, s = u & 7;
            const int ek = s ^ (j & 7);
            const int e = (ek >> 2) & 1, ks = ek & 3;
            async16(src + (size_t)(2 * j + e) * CC + kbase + ks * 8,
                    base + u * 16);
        }
    };

    // fragment byte offsets within a 16KB region (pair-XOR; +16 rows = +1024)
    const int slot = ((((fr & 1) << 2) | fg) ^ ((fr >> 1) & 7));
    const int offA = (wm * 64 + (fr >> 1)) * 128 + slot * 16;           // +mf*1024
    const int offB = 32768 + (wn * 32 + (fr >> 1)) * 128 + slot * 16;   // +nf*1024

    fx4 acc[8][4];
#pragma unroll
    for (int i = 0; i < 8; ++i)
#pragma unroll
        for (int j = 0; j < 4; ++j)
            acc[i][j] = (fx4){0.f, 0.f, 0.f, 0.f};

    // prologue: tile 0 all 4 groups + tile 1 group 0 (10 loads/thread)
#pragma unroll
    for (int g = 0; g < 4; ++g) STAGE_G(0, g);
    STAGE_G(1, 0);

#pragma unroll 1
    for (int t = 0; t < nt; ++t) {
        const char* kb = Gsm[t & 1];
#pragma unroll
        for (int kk = 0; kk < 2; ++kk) {
            // ---- tile boundary (kk0 only): counted, never drains mid-loop
            if (kk == 0) {
                if (t == nt - 1) {
                    asm volatile("s_waitcnt vmcnt(0)" ::: "memory");
                } else {
                    asm volatile("s_waitcnt vmcnt(2)" ::: "memory");
                }
                __builtin_amdgcn_sched_barrier(0);
                __builtin_amdgcn_s_barrier();
                __builtin_amdgcn_sched_barrier(0);
            }

            const char* ka = kb + kk * 16384;           // A region, this k-half
            const char* kbB = kb + kk * 16384;          // B region base added via offB
            bh8 afr[4], bfr[4];

            // ---- P_even: reads (B all nf + A mf0-3), stage, barrier, MFMA ----
#pragma unroll
            for (int nf = 0; nf < 4; ++nf)
                bfr[nf] = *(const bh8*)(kbB + offB + nf * 1024);
#pragma unroll
            for (int i = 0; i < 4; ++i)
                afr[i] = *(const bh8*)(ka + offA + i * 1024);
            STAGE_G(t + 1, kk ? 3 : 1);

            __builtin_amdgcn_sched_barrier(0);
            __builtin_amdgcn_s_barrier();
            __builtin_amdgcn_sched_barrier(0);

            __builtin_amdgcn_s_setprio(1);
#pragma unroll
            for (int i = 0; i < 4; ++i)
#pragma unroll
                for (int nf = 0; nf < 4; ++nf)
                    acc[i][nf] = __builtin_amdgcn_mfma_f32_16x16x32_bf16(
                        afr[i], bfr[nf], acc[i][nf], 0, 0, 0);
            __builtin_amdgcn_s_setprio(0);

            // ---- P_odd: reads (A mf4-7), stage, barrier, MFMA ----
#pragma unroll
            for (int i = 0; i < 4; ++i)
                afr[i] = *(const bh8*)(ka + offA + (4 + i) * 1024);
            if (kk) STAGE_G(t + 2, 0);
            else    STAGE_G(t + 1, 2);

            __builtin_amdgcn_sched_barrier(0);
            __builtin_amdgcn_s_barrier();
            __builtin_amdgcn_sched_barrier(0);

            __builtin_amdgcn_s_setprio(1);
#pragma unroll
            for (int i = 0; i < 4; ++i)
#pragma unroll
                for (int nf = 0; nf < 4; ++nf)
                    acc[4 + i][nf] = __builtin_amdgcn_mfma_f32_16x16x32_bf16(
                        afr[i], bfr[nf], acc[4 + i][nf], 0, 0, 0);
            __builtin_amdgcn_s_setprio(0);
        }
    }

    if (OUTF == 2) {
        // ---- V epilogue: write directly in Vt layout [bh][d][pnew(t)] ----
        // acc row = m0+wm*128+mf*16+fg*4+r. Pair mf=2*mfp (jj=0) with
        // mf=2*mfp+1 (jj=1): t in 32-block rowb=m0+wm*128+mfp*32 at
        // pnew-local = fg*8 + jj*4 + r -> 8 contiguous ushorts per lane.
        ushort* Vt = (ushort*)Cv;
#pragma unroll
        for (int nf = 0; nf < 4; ++nf) {
            const int col = n0 + wn * 64 + nf * 16 + fr;
            const int h = col >> 7, d = col & 127;
            const float bv = bias[col];
#pragma unroll
            for (int mfp = 0; mfp < 4; ++mfp) {
                const int rowb = m0 + wm * 128 + mfp * 32;   // 32-aligned t-blk
                const int b = rowb >> 11;                     // batch
                const int tloc = (rowb & (TT - 1)) + fg * 8;
                union { ushort u[8]; uint4 v; } pk;
#pragma unroll
                for (int r = 0; r < 4; ++r) {
                    pk.u[r]     = f2bf(acc[2 * mfp][nf][r] + bv);
                    pk.u[4 + r] = f2bf(acc[2 * mfp + 1][nf][r] + bv);
                }
                *(uint4*)&Vt[((size_t)((b * HH + h) * DD + d)) * TT + tloc] = pk.v;
            }
        }
        return;
    }

    // epilogue: C/D layout col=lane&15, row=(lane>>4)*4+reg
#pragma unroll
    for (int nf = 0; nf < 4; ++nf) {
        const int col = n0 + wn * 64 + nf * 16 + fr;
        const float bv = bias[col];
#pragma unroll
        for (int mf = 0; mf < 8; ++mf) {
            const int row = m0 + wm * 128 + mf * 16 + fg * 4;
#pragma unroll
            for (int r = 0; r < 4; ++r) {
                float v = (acc[mf][nf][r] + bv) * osc;
                if (OUTF)
                    ((float*)Cv)[(size_t)(row + r) * CC + col] = v;
                else
                    ((ushort*)Cv)[(size_t)(row + r) * CC + col] = f2bf(v);
            }
        }
    }
}

// Fused Q/K/V projection GEMM: grid (256, 3), blockIdx.y selects tensor.
// y=2 (V) writes directly in Vt layout (OUTF=2) -> no transpose_v kernel.
// Shared LDS declared HERE (one 128KB array shared by all inlined bodies).
__global__ __launch_bounds__(512, 2) void gemm_qkv_k(
    const ushort* __restrict__ Xq, const ushort* __restrict__ Xk,
    const ushort* __restrict__ Xv,
    const ushort* __restrict__ WqT, const ushort* __restrict__ WkT,
    const ushort* __restrict__ WvT,
    const float* __restrict__ bq, const float* __restrict__ bk,
    const float* __restrict__ bv,
    ushort* __restrict__ Qb, ushort* __restrict__ Kb, ushort* __restrict__ Vt)
{
    __shared__ __align__(16) char Gsm[2][65536];  // [dbuf][A.k0|A.k1|B.k0|B.k1]
    if (blockIdx.y == 0) {
        gemm_body<0>(Gsm, Xq, WqT, bq, Qb, 0.12751789836306614f); // log2e/sqrt(128)
    } else if (blockIdx.y == 1) {
        gemm_body<0>(Gsm, Xk, WkT, bk, Kb, 1.0f);
    } else {
        gemm_body<2>(Gsm, Xv, WvT, bv, Vt, 1.0f);
    }
}

// Output projection GEMM (fp32 out)
__global__ __launch_bounds__(512, 2) void gemm_o_k(
    const ushort* __restrict__ A, const ushort* __restrict__ Bt,
    const float* __restrict__ bias, float* __restrict__ Cv)
{
    __shared__ __align__(16) char Gsm[2][65536];
    gemm_body<1>(Gsm, A, Bt, bias, Cv, 1.0f);
}

// ---------------------------------------------------------------------------
// Flash attention v13 (round-4 verified, ~105us): one barrier per KV-tile,
// STAGE after the barrier, swapped-QK^T in-register softmax, ones-MFMA
// denominator, diagonal-tile skip, tile pairing, XCD swizzle. UNCHANGED.
// ---------------------------------------------------------------------------
__global__ __launch_bounds__(512, 4) void flash_attn_k(
    const ushort* __restrict__ Qm, const ushort* __restrict__ Km,
    const ushort* __restrict__ Vt, ushort* __restrict__ Om,
    const int* __restrict__ causal_p)
{
    __shared__ __align__(16) char Ksm[2][16384];   // [buf][kv=64][d=128] bf16
    __shared__ __align__(16) char Vsm[2][16384];   // [buf][d=128][pos=64] bf16

    const int tid = (int)threadIdx.x;
    const int lane = tid & 63, wave = tid >> 6;
    const int fr = lane & 15, fg = lane >> 4;
    const int causal = causal_p[0];

    const int d_raw = (int)blockIdx.x + 8 * ((int)blockIdx.y + 16 * (int)blockIdx.z);
    const int xcd = d_raw & 7, jj = d_raw >> 3;
    const int head_lin = xcd * 8 + (jj & 7);
    const int pi = jj >> 3;                   // 0..7 (pair index)
    const int h = head_lin & 15, b = head_lin >> 4;

    const ushort* Qp = Qm + (size_t)b * TT * CC + h * DD;
    const ushort* Kp = Km + (size_t)b * TT * CC + h * DD;
    const ushort* Vp = Vt + (size_t)(b * HH + h) * DD * TT;
    ushort* Op = Om + (size_t)b * TT * CC + h * DD;

    // all-ones bf16 B-fragment for the row-sum MFMA
    const bh8 onesf = {0x3F80, 0x3F80, 0x3F80, 0x3F80,
                       0x3F80, 0x3F80, 0x3F80, 0x3F80};

    auto STAGE = [&](int ti, int buf) {
        const int kv0 = ti * 64;
        {
            const int r0 = tid >> 4, s0 = tid & 15;
            async16(Kp + (size_t)(kv0 + r0) * CC + (s0 ^ (r0 & 15)) * 8,
                    Ksm[buf] + tid * 16);
            async16(Kp + (size_t)(kv0 + 32 + r0) * CC + (s0 ^ (r0 & 15)) * 8,
                    Ksm[buf] + 8192 + tid * 16);
        }
        {
            const int d0 = tid >> 3, s0 = tid & 7;
            async16(Vp + (size_t)d0 * TT + kv0 + (s0 ^ (d0 & 7)) * 8,
                    Vsm[buf] + tid * 16);
            async16(Vp + (size_t)(64 + d0) * TT + kv0 + (s0 ^ (d0 & 7)) * 8,
                    Vsm[buf] + 8192 + tid * 16);
        }
    };

#pragma unroll 1
    for (int pp = 0; pp < 2; ++pp) {
        const int tile = pp ? (15 - pi) : pi;
        const int q0 = tile * 128;
        const int qbase = q0 + wave * 16;
        const int q_idx = qbase + fr;         // this lane's q-row (swapped layout)

        bh8 qf[4];
#pragma unroll
        for (int s = 0; s < 4; ++s)
            qf[s] = *(const bh8*)&Qp[(size_t)(qbase + fr) * CC + s * 32 + fg * 8];

        fx4 o[8];
#pragma unroll
        for (int jn = 0; jn < 8; ++jn) o[jn] = (fx4){0.f, 0.f, 0.f, 0.f};
        fx4 o_l = (fx4){0.f, 0.f, 0.f, 0.f};

        const int nfull  = causal ? (q0 >> 6) : (TT / 64);
        const int ntiles = causal ? (nfull + 2) : (TT / 64);

        STAGE(0, 0);
#pragma unroll 1
        for (int t = 0; t < ntiles; ++t) {
            // top sync: own loads done -> barrier -> everyone's loads done
            asm volatile("s_waitcnt vmcnt(0)" ::: "memory");
            __builtin_amdgcn_sched_barrier(0);
            __builtin_amdgcn_s_barrier();
            __builtin_amdgcn_sched_barrier(0);
            if (t + 1 < ntiles) STAGE(t + 1, (t + 1) & 1);

            const int kv0 = t * 64;
            const char* kb = Ksm[t & 1];
            const char* vb = Vsm[t & 1];
            const bool domask = causal && (t >= nfull);
            const bool active = !domask || (kv0 <= qbase + 15);

            if (active) {
                // ---- QK^T, swapped: S^T layout; lane holds q=fr, kv=j*16+fg*4+r
                fx4 s4[4];
#pragma unroll
                for (int j = 0; j < 4; ++j) s4[j] = (fx4){0.f, 0.f, 0.f, 0.f};
                __builtin_amdgcn_s_setprio(1);
#pragma unroll
                for (int st = 0; st < 4; ++st) {
                    bh8 kf[4];
#pragma unroll
                    for (int j = 0; j < 4; ++j)
                        kf[j] = *(const bh8*)(kb + (j * 16 + fr) * 256 +
                                              ((st * 64 + fg * 16) ^ (fr << 4)));
#pragma unroll
                    for (int j = 0; j < 4; ++j)
                        s4[j] = __builtin_amdgcn_mfma_f32_16x16x32_bf16(
                            kf[j], qf[st], s4[j], 0, 0, 0);
                }
                __builtin_amdgcn_s_setprio(0);

                // ---- softmax + PV per 32-kv half; P never leaves registers
#pragma unroll
                for (int g = 0; g < 2; ++g) {
                    float pg[2][4];
#pragma unroll
                    for (int j2 = 0; j2 < 2; ++j2) {
                        const int jb = g * 2 + j2;
#pragma unroll
                        for (int r = 0; r < 4; ++r) {
                            float v = s4[jb][r];
                            if (domask && (kv0 + jb * 16 + fg * 4 + r > q_idx))
                                v = -1e30f;
                            pg[j2][r] = exp2f(v);
                        }
                    }
                    // pack to PV A-fragment: k-slot e = jj*4 + r
                    union { uint u[4]; bh8 h; } pk;
                    asm("v_cvt_pk_bf16_f32 %0, %1, %2"
                        : "=v"(pk.u[0]) : "v"(pg[0][0]), "v"(pg[0][1]));
                    asm("v_cvt_pk_bf16_f32 %0, %1, %2"
                        : "=v"(pk.u[1]) : "v"(pg[0][2]), "v"(pg[0][3]));
                    asm("v_cvt_pk_bf16_f32 %0, %1, %2"
                        : "=v"(pk.u[2]) : "v"(pg[1][0]), "v"(pg[1][1]));
                    asm("v_cvt_pk_bf16_f32 %0, %1, %2"
                        : "=v"(pk.u[3]) : "v"(pg[1][2]), "v"(pg[1][3]));
                    const bh8 pf = pk.h;

                    // denominator via matrix pipe: row-sum of this 32-kv half,
                    // D row = fg*4+r (matches epilogue rows), replicated on fr
                    o_l = __builtin_amdgcn_mfma_f32_16x16x32_bf16(
                        pf, onesf, o_l, 0, 0, 0);

                    __builtin_amdgcn_s_setprio(1);
#pragma unroll
                    for (int jn = 0; jn < 8; ++jn) {
                        bh8 vf = *(const bh8*)(vb + (jn * 16 + fr) * 128 +
                                               ((g * 64 + fg * 16) ^ ((fr & 7) << 4)));
                        o[jn] = __builtin_amdgcn_mfma_f32_16x16x32_bf16(
                            pf, vf, o[jn], 0, 0, 0);
                    }
                    __builtin_amdgcn_s_setprio(0);
                }
            }
        }

        // ---- epilogue: l already per-lane in D-layout (no shuffles)
#pragma unroll
        for (int r = 0; r < 4; ++r) {
            const float inv = 1.0f / o_l[r];
            const size_t rowoff = (size_t)(qbase + fg * 4 + r) * CC;
#pragma unroll
            for (int jn = 0; jn < 8; ++jn)
                Op[rowoff + jn * 16 + fr] = f2bf(o[jn][r] * inv);
        }
    }
}

// ---------------------------------------------------------------------------
extern "C" void kernel_launch(void* const* d_in, const int* in_sizes, int n_in,
                              void* d_out, int out_size, void* d_ws, size_t ws_size,
                              hipStream_t stream)
{
    (void)in_sizes; (void)n_in; (void)out_size;
    const float* querys = (const float*)d_in[0];
    const float* keys   = (const float*)d_in[1];
    const float* values = (const float*)d_in[2];
    const float* Wq = (const float*)d_in[3];
    const float* bq = (const float*)d_in[4];
    const float* Wk = (const float*)d_in[5];
    const float* bk = (const float*)d_in[6];
    const float* Wv = (const float*)d_in[7];
    const float* bv = (const float*)d_in[8];
    const float* Wo = (const float*)d_in[9];
    const float* bo = (const float*)d_in[10];
    const int* is_causal = (const int*)d_in[11];

    const size_t WBYTES = (size_t)CC * CC * 2;   // 8 MiB per weight
    const size_t XBYTES = (size_t)MM * CC * 2;   // 32 MiB per activation
    if (ws_size < 4 * WBYTES + 4 * XBYTES) return;  // need 160 MiB

    uint8_t* ws = (uint8_t*)d_ws;
    ushort* WqT = (ushort*)(ws);
    ushort* WkT = (ushort*)(ws + WBYTES);
    ushort* WvT = (ushort*)(ws + 2 * WBYTES);
    ushort* WoT = (ushort*)(ws + 3 * WBYTES);
    uint8_t* act = ws + 4 * WBYTES;
    ushort* Xq = (ushort*)(act);                 // later: Kb
    ushort* Xk = (ushort*)(act + XBYTES);        // later: Vt
    ushort* Xv = (ushort*)(act + 2 * XBYTES);    // later: Ob (attn out)
    ushort* Qb = (ushort*)(act + 3 * XBYTES);
    ushort* Kb = Xq;    // K proj writes over its own dispatch-ordered input
    ushort* Vt = Xk;    // V proj writes Vt layout here (Xk dead after K round)
    ushort* Ob = Xv;    // attn output overwrites Xv (dead after V round)

    dim3 tb(32, 8);
    transpose4_w_k<<<dim3(CC / 32, CC / 32, 4), tb, 0, stream>>>(
        Wq, Wk, Wv, Wo, WqT, WkT, WvT, WoT);

    const int nX = MM * CC;
    convert3_k<<<dim3(nX / 4 / 256, 3), 256, 0, stream>>>(
        querys, keys, values, Xq, Xk, Xv, nX);

    // fused Q/K/V projections; V writes Vt layout directly (no transpose_v)
    gemm_qkv_k<<<dim3((MM / 256) * (CC / 256), 3), 512, 0, stream>>>(
        Xq, Xk, Xv, WqT, WkT, WvT, bq, bk, bv, Qb, Kb, Vt);

    dim3 ga(8, HH, BB);   // pair index x head x batch, 512 threads
    flash_attn_k<<<ga, 512, 0, stream>>>(Qb, Kb, Vt, Ob, is_causal);

    gemm_o_k<<<dim3((MM / 256) * (CC / 256)), 512, 0, stream>>>(
        Ob, WoT, bo, (float*)d_out);
}